// Round 4
// baseline (1236.461 us; speedup 1.0000x reference)
//
#include <hip/hip_runtime.h>
#include <hip/hip_bf16.h>
#include <math.h>

// ---------- common types ----------
typedef unsigned short u16;
typedef __attribute__((ext_vector_type(8))) short short8;  // 8 bf16 = 4 VGPRs (MFMA A/B frag)
typedef __attribute__((ext_vector_type(4))) float f32x4;   // MFMA C/D frag

#define CDIM 1024
#define TDIM 1024
#define NROWS 2048   // B*T
#define HEADS 16
#define HD 64
#define F4 4096

// round-to-nearest-even fp32 -> bf16 bits
__device__ __forceinline__ u16 f2bf(float f) {
    union { float f; unsigned u; } v; v.f = f;
    unsigned r = v.u + 0x7fffu + ((v.u >> 16) & 1u);
    return (u16)(r >> 16);
}

// async global->LDS, 16 bytes per lane; lds base must be wave-uniform
__device__ __forceinline__ void gload_lds16(const void* g, void* lds) {
    __builtin_amdgcn_global_load_lds(
        (const __attribute__((address_space(1))) unsigned int*)g,
        (__attribute__((address_space(3))) unsigned int*)lds,
        16, 0, 0);
}

// ---------- embedding: x = tok_emb[tok] + pos_emb ----------
__global__ __launch_bounds__(256)
void embed_k(const int* __restrict__ tok, const float* __restrict__ te,
             const float* __restrict__ pe, float* __restrict__ X)
{
    const int row = blockIdx.x;          // b*1024 + t
    const int t = row & (TDIM - 1);
    const int tk = tok[row];
    const int c = threadIdx.x * 4;
    float4 a = *reinterpret_cast<const float4*>(te + (size_t)tk * CDIM + c);
    float4 b = *reinterpret_cast<const float4*>(pe + (size_t)t * CDIM + c);
    a.x += b.x; a.y += b.y; a.z += b.z; a.w += b.w;
    *reinterpret_cast<float4*>(X + (size_t)row * CDIM + c) = a;
}

// ---------- layernorm over C=1024, fp32 stats; out bf16 or fp32 ----------
template<bool BF16OUT>
__global__ __launch_bounds__(256)
void ln_k(const float* __restrict__ X, const float* __restrict__ g,
          const float* __restrict__ be, void* __restrict__ outp)
{
    __shared__ float red[4], red2[4];
    const int row = blockIdx.x, tid = threadIdx.x;
    const float* xr = X + (size_t)row * CDIM;
    const int c = tid * 4;
    float4 xv = *reinterpret_cast<const float4*>(xr + c);
    float s  = xv.x + xv.y + xv.z + xv.w;
    float s2 = xv.x*xv.x + xv.y*xv.y + xv.z*xv.z + xv.w*xv.w;
    #pragma unroll
    for (int off = 32; off; off >>= 1) {
        s  += __shfl_xor(s, off);
        s2 += __shfl_xor(s2, off);
    }
    if ((tid & 63) == 0) { red[tid >> 6] = s; red2[tid >> 6] = s2; }
    __syncthreads();
    const float ts  = red[0] + red[1] + red[2] + red[3];
    const float ts2 = red2[0] + red2[1] + red2[2] + red2[3];
    const float mu  = ts * (1.0f / CDIM);
    const float var = ts2 * (1.0f / CDIM) - mu * mu;
    const float rs  = rsqrtf(var + 1e-5f);
    float4 gv = *reinterpret_cast<const float4*>(g + c);
    float4 bv = *reinterpret_cast<const float4*>(be + c);
    float o0 = (xv.x - mu) * rs * gv.x + bv.x;
    float o1 = (xv.y - mu) * rs * gv.y + bv.y;
    float o2 = (xv.z - mu) * rs * gv.z + bv.z;
    float o3 = (xv.w - mu) * rs * gv.w + bv.w;
    if (BF16OUT) {
        u16 tmp[4] = { f2bf(o0), f2bf(o1), f2bf(o2), f2bf(o3) };
        u16* o = (u16*)outp + (size_t)row * CDIM + c;
        *reinterpret_cast<uint2*>(o) = *reinterpret_cast<const uint2*>(tmp);
    } else {
        float4 ov = { o0, o1, o2, o3 };
        *reinterpret_cast<float4*>((float*)outp + (size_t)row * CDIM + c) = ov;
    }
}

// ---------- weight convert+transpose: W[K][N] fp32 -> Wt[N][K] bf16 ----------
__global__ __launch_bounds__(256)
void convT_k(const float* __restrict__ W, u16* __restrict__ Wt,
             const int K, const int N)
{
    __shared__ u16 s[64][72];
    const int k0 = blockIdx.y * 64, n0 = blockIdx.x * 64;
    const int tr = threadIdx.x >> 4, tc = (threadIdx.x & 15) * 4;
    #pragma unroll
    for (int i = 0; i < 4; ++i) {
        int r = tr + i * 16;
        float4 w = *reinterpret_cast<const float4*>(W + (size_t)(k0 + r) * N + n0 + tc);
        s[r][tc + 0] = f2bf(w.x); s[r][tc + 1] = f2bf(w.y);
        s[r][tc + 2] = f2bf(w.z); s[r][tc + 3] = f2bf(w.w);
    }
    __syncthreads();
    #pragma unroll
    for (int i = 0; i < 4; ++i) {
        int n = tr + i * 16;
        u16 tmp[4];
        #pragma unroll
        for (int e = 0; e < 4; ++e) tmp[e] = s[tc + e][n];
        *reinterpret_cast<uint2*>(Wt + (size_t)(n0 + n) * K + k0 + tc) =
            *reinterpret_cast<const uint2*>(tmp);
    }
}

// ---------- GEMM: C[M][N] = A_bf16[M][K] @ Bt_bf16[N][K]^T ----------
// 64(M)x128(N) tile, 4 waves (2m x 2n), each 32x64 via 2x4 16x16x32 frags.
// Double-buffered LDS via global_load_lds, ONE barrier per K-step; grid.z = split-K.
// EPI 0: out bf16 (+optional V-transpose region)  EPI 1: gelu->bf16  EPI 2: atomicAdd fp32
template<int EPI>
__global__ __launch_bounds__(256)
void gemm_bt(const u16* __restrict__ A, const u16* __restrict__ Bt,
             const float* __restrict__ bias, u16* __restrict__ outb,
             float* __restrict__ resid, u16* __restrict__ vtout,
             const int N, const int K, const int KCH)
{
    __shared__ __align__(16) u16 sA[2][64 * 32];    // [row][k] 64B rows, no pad
    __shared__ __align__(16) u16 sB[2][128 * 32];
    const int tid = threadIdx.x;
    const int lane = tid & 63, wv = tid >> 6;
    const int m0 = blockIdx.y * 64, n0 = blockIdx.x * 128;
    const int kbeg = blockIdx.z * KCH, kend = kbeg + KCH;
    const int fr = lane & 15, fq = lane >> 4;
    const int wm = wv & 1, wn = wv >> 1;
    const int srow = lane >> 2, sch = (lane & 3) * 8;   // 4 lanes/row, 16B chunks
    f32x4 acc[2][4] = {};

    auto stage = [&](int k0, int buf) {
        gload_lds16(A + (size_t)(m0 + wv * 16 + srow) * K + k0 + sch,
                    &sA[buf][wv * 16 * 32]);
        #pragma unroll
        for (int i = 0; i < 2; ++i)
            gload_lds16(Bt + (size_t)(n0 + i * 64 + wv * 16 + srow) * K + k0 + sch,
                        &sB[buf][(i * 64 + wv * 16) * 32]);
    };

    stage(kbeg, 0);
    int cur = 0;
    for (int k0 = kbeg; k0 < kend; k0 += 32) {
        __syncthreads();                          // buf[cur] staged
        if (k0 + 32 < kend) stage(k0 + 32, cur ^ 1);
        short8 af[2], bf[4];
        #pragma unroll
        for (int mi = 0; mi < 2; ++mi)
            af[mi] = *reinterpret_cast<const short8*>(&sA[cur][(wm * 32 + mi * 16 + fr) * 32 + fq * 8]);
        #pragma unroll
        for (int nj = 0; nj < 4; ++nj)
            bf[nj] = *reinterpret_cast<const short8*>(&sB[cur][(wn * 64 + nj * 16 + fr) * 32 + fq * 8]);
        #pragma unroll
        for (int mi = 0; mi < 2; ++mi)
            #pragma unroll
            for (int nj = 0; nj < 4; ++nj)
                acc[mi][nj] = __builtin_amdgcn_mfma_f32_16x16x32_bf16(af[mi], bf[nj], acc[mi][nj], 0, 0, 0);
        cur ^= 1;
    }

    #pragma unroll
    for (int nj = 0; nj < 4; ++nj) {
        const int col = n0 + wn * 64 + nj * 16 + fr;
        const float bias_v = (EPI == 2 && blockIdx.z != 0) ? 0.0f : bias[col];
        #pragma unroll
        for (int mi = 0; mi < 2; ++mi) {
            const int rowb = m0 + wm * 32 + mi * 16 + fq * 4;
            if (EPI == 0 && vtout != nullptr && col >= 2048) {
                // V part of qkv -> transposed [b*16+h][d][t] bf16, packed 4 t's
                const int bidx = rowb >> 10, t = rowb & 1023, hd = col - 2048;
                u16 t4[4];
                #pragma unroll
                for (int r = 0; r < 4; ++r) t4[r] = f2bf(acc[mi][nj][r] + bias_v);
                *reinterpret_cast<uint2*>(
                    vtout + ((size_t)(bidx * 16 + (hd >> 6)) * 64 + (hd & 63)) * 1024 + t) =
                    *reinterpret_cast<const uint2*>(t4);
            } else {
                #pragma unroll
                for (int r = 0; r < 4; ++r) {
                    const int row = rowb + r;
                    float cv = acc[mi][nj][r] + bias_v;
                    if (EPI == 0) {
                        outb[(size_t)row * N + col] = f2bf(cv);
                    } else if (EPI == 1) {
                        float gl = 0.5f * cv * (1.0f + erff(cv * 0.70710678118654752f));
                        outb[(size_t)row * N + col] = f2bf(gl);
                    } else {
                        atomicAdd(&resid[(size_t)row * N + col], cv);
                    }
                }
            }
        }
    }
}

// ---------- flash attention: QKV [row][3072] (q,k) + VT [b*16+h][d][t]; per-block (qt,h,b) ----------
// Register online-softmax, wave-private P through LDS, dbuf K/V, 1 barrier/s-tile.
__global__ __launch_bounds__(256)
void attn_k(const u16* __restrict__ QKV, const u16* __restrict__ VT,
            u16* __restrict__ Y)
{
    __shared__ __align__(16) u16 sQ[64][72];
    __shared__ __align__(16) u16 sK[2][64][72];
    __shared__ __align__(16) u16 sV[2][64][72];   // [d][s]
    __shared__ __align__(16) u16 sP[64][72];
    const int tid = threadIdx.x, lane = tid & 63, wv = tid >> 6;
    const int fr = lane & 15, fq = lane >> 4;
    const int qt = blockIdx.x, h = blockIdx.y, b = blockIdx.z, q0 = qt * 64;
    const u16* Qb = QKV + (size_t)b * TDIM * 3072 + h * HD;
    const u16* Vb = VT + ((size_t)(b * HEADS + h) * HD) * TDIM;
    const int r0 = tid >> 3, c0 = (tid & 7) * 8;   // staging: 8 chunks/row

    #pragma unroll
    for (int i = 0; i < 2; ++i) {
        const int r = r0 + i * 32;
        *reinterpret_cast<uint4*>(&sQ[r][c0]) =
            *reinterpret_cast<const uint4*>(Qb + (size_t)(q0 + r) * 3072 + c0);
        *reinterpret_cast<uint4*>(&sK[0][r][c0]) =
            *reinterpret_cast<const uint4*>(Qb + 1024 + (size_t)r * 3072 + c0);
        *reinterpret_cast<uint4*>(&sV[0][r][c0]) =
            *reinterpret_cast<const uint4*>(Vb + (size_t)r * TDIM + c0);
    }
    __syncthreads();

    short8 aQ0 = *reinterpret_cast<const short8*>(&sQ[wv * 16 + fr][fq * 8]);
    short8 aQ1 = *reinterpret_cast<const short8*>(&sQ[wv * 16 + fr][32 + fq * 8]);
    f32x4 o[4] = {};
    float m_run[4], l_run[4];
    #pragma unroll
    for (int r = 0; r < 4; ++r) { m_run[r] = -1e30f; l_run[r] = 0.0f; }

    for (int st = 0; st <= qt; ++st) {
        const int cur = st & 1, s0 = st * 64;
        const bool pf = st < qt;
        uint4 pk[2], pv[2];
        if (pf) {
            #pragma unroll
            for (int i = 0; i < 2; ++i) {
                const int r = r0 + i * 32;
                pk[i] = *reinterpret_cast<const uint4*>(Qb + 1024 + (size_t)(s0 + 64 + r) * 3072 + c0);
                pv[i] = *reinterpret_cast<const uint4*>(Vb + (size_t)r * TDIM + s0 + 64 + c0);
            }
        }
        // S = Q K^T (fp32)
        f32x4 sacc[4] = {};
        #pragma unroll
        for (int j = 0; j < 4; ++j) {
            short8 b0 = *reinterpret_cast<const short8*>(&sK[cur][j * 16 + fr][fq * 8]);
            sacc[j] = __builtin_amdgcn_mfma_f32_16x16x32_bf16(aQ0, b0, sacc[j], 0, 0, 0);
            short8 b1 = *reinterpret_cast<const short8*>(&sK[cur][j * 16 + fr][32 + fq * 8]);
            sacc[j] = __builtin_amdgcn_mfma_f32_16x16x32_bf16(aQ1, b1, sacc[j], 0, 0, 0);
        }
        // mask + scale into registers
        float S[4][4];   // [j][r]
        #pragma unroll
        for (int j = 0; j < 4; ++j)
            #pragma unroll
            for (int r = 0; r < 4; ++r) {
                const int qrow = q0 + wv * 16 + fq * 4 + r;
                const int scol = s0 + j * 16 + fr;
                const bool keep = (scol <= qrow) && ((scol & 15) != 15);
                S[j][r] = keep ? sacc[j][r] * 0.125f : -1e30f;
            }
        // register online softmax (reduce over fr lanes: offsets 1,2,4,8)
        float al[4];
        #pragma unroll
        for (int r = 0; r < 4; ++r) {
            float mx = fmaxf(fmaxf(S[0][r], S[1][r]), fmaxf(S[2][r], S[3][r]));
            mx = fmaxf(mx, __shfl_xor(mx, 1));
            mx = fmaxf(mx, __shfl_xor(mx, 2));
            mx = fmaxf(mx, __shfl_xor(mx, 4));
            mx = fmaxf(mx, __shfl_xor(mx, 8));
            const float mnew = fmaxf(m_run[r], mx);
            al[r] = __expf(m_run[r] - mnew);
            float ls = 0.0f;
            #pragma unroll
            for (int j = 0; j < 4; ++j) {
                const float p = __expf(S[j][r] - mnew);
                S[j][r] = p; ls += p;
            }
            ls += __shfl_xor(ls, 1);
            ls += __shfl_xor(ls, 2);
            ls += __shfl_xor(ls, 4);
            ls += __shfl_xor(ls, 8);
            l_run[r] = l_run[r] * al[r] + ls;
            m_run[r] = mnew;
        }
        // P -> LDS (wave-private rows), rescale O
        #pragma unroll
        for (int j = 0; j < 4; ++j)
            #pragma unroll
            for (int r = 0; r < 4; ++r)
                sP[wv * 16 + fq * 4 + r][j * 16 + fr] = f2bf(S[j][r]);
        #pragma unroll
        for (int j = 0; j < 4; ++j)
            #pragma unroll
            for (int r = 0; r < 4; ++r) o[j][r] *= al[r];
        short8 aP0 = *reinterpret_cast<const short8*>(&sP[wv * 16 + fr][fq * 8]);
        short8 aP1 = *reinterpret_cast<const short8*>(&sP[wv * 16 + fr][32 + fq * 8]);
        #pragma unroll
        for (int j = 0; j < 4; ++j) {
            short8 b0 = *reinterpret_cast<const short8*>(&sV[cur][j * 16 + fr][fq * 8]);
            o[j] = __builtin_amdgcn_mfma_f32_16x16x32_bf16(aP0, b0, o[j], 0, 0, 0);
            short8 b1 = *reinterpret_cast<const short8*>(&sV[cur][j * 16 + fr][32 + fq * 8]);
            o[j] = __builtin_amdgcn_mfma_f32_16x16x32_bf16(aP1, b1, o[j], 0, 0, 0);
        }
        if (pf) {
            #pragma unroll
            for (int i = 0; i < 2; ++i) {
                const int r = r0 + i * 32;
                *reinterpret_cast<uint4*>(&sK[cur ^ 1][r][c0]) = pk[i];
                *reinterpret_cast<uint4*>(&sV[cur ^ 1][r][c0]) = pv[i];
            }
        }
        __syncthreads();
    }

    const size_t ybase = ((size_t)b * TDIM + q0) * CDIM + h * HD;
    #pragma unroll
    for (int j = 0; j < 4; ++j)
        #pragma unroll
        for (int r = 0; r < 4; ++r) {
            const int row = wv * 16 + fq * 4 + r, col = j * 16 + fr;
            Y[ybase + (size_t)row * CDIM + col] = f2bf(o[j][r] / l_run[r]);
        }
}

// ---------- head: logits[b,p,o] = sum_i head_w[p%16, o, i] * x[b,p,i] (fp32) ----------
__global__ __launch_bounds__(256)
void head_k(const float* __restrict__ Xf, const float* __restrict__ HW,
            float* __restrict__ out)
{
    const int row = blockIdx.x;               // b*1024 + p
    const int e = row & 15;                   // 1024 % 16 == 0 so row%16 == p%16
    const float* xr = Xf + (size_t)row * CDIM;
    const float* wbase = HW + (size_t)e * 101 * CDIM;
    const int lane = threadIdx.x & 63, wv = threadIdx.x >> 6;
    for (int o = wv; o < 101; o += 4) {
        const float* wr = wbase + (size_t)o * CDIM;
        float s = 0.0f;
        #pragma unroll
        for (int i = 0; i < CDIM / 64; ++i)
            s += xr[lane + i * 64] * wr[lane + i * 64];
        #pragma unroll
        for (int off = 32; off; off >>= 1) s += __shfl_xor(s, off);
        if (lane == 0) out[(size_t)row * 101 + o] = s;
    }
}

// ---------- launch ----------
extern "C" void kernel_launch(void* const* d_in, const int* in_sizes, int n_in,
                              void* d_out, int out_size, void* d_ws, size_t ws_size,
                              hipStream_t stream)
{
    const int*   tokens = (const int*)  d_in[0];
    const float* tok_emb= (const float*)d_in[1];
    const float* pos_emb= (const float*)d_in[2];
    const float* Wq = (const float*)d_in[3];
    const float* bq = (const float*)d_in[4];
    const float* Wk = (const float*)d_in[5];
    const float* bk = (const float*)d_in[6];
    const float* Wv = (const float*)d_in[7];
    const float* bv = (const float*)d_in[8];
    const float* Wp = (const float*)d_in[9];
    const float* bp = (const float*)d_in[10];
    const float* ln1w = (const float*)d_in[11];
    const float* ln1b = (const float*)d_in[12];
    const float* ln2w = (const float*)d_in[13];
    const float* ln2b = (const float*)d_in[14];
    const float* W1 = (const float*)d_in[15];
    const float* b1 = (const float*)d_in[16];
    const float* W2 = (const float*)d_in[17];
    const float* b2 = (const float*)d_in[18];
    const float* lnfw = (const float*)d_in[19];
    const float* lnfb = (const float*)d_in[20];
    const float* head_w = (const float*)d_in[21];
    float* out = (float*)d_out;

    // workspace (36 MB + 12 KB):
    //  0..8M    x fp32 residual
    //  8..12M   hbuf bf16 (LN out) == yb bf16 (attn out; disjoint in time)
    // 12..24M   qkv bf16 [2048][3072] (q,k used)     } alias: mid bf16 [2048][4096] (12..28M),
    // 24..28M   vT bf16 [b*16+h][64][1024]           }        hf fp32 (12..20M, final)
    // 28..36M   wbuf bf16 (converted weights, max 8MB)
    // 36M..     bbuf fp32 [3072]
    char* ws = (char*)d_ws;
    float* x    = (float*)(ws);
    u16*   hbuf = (u16*)  (ws + (8u  << 20));
    u16*   yb   = (u16*)  (ws + (8u  << 20));
    u16*   qkv  = (u16*)  (ws + (12u << 20));
    u16*   vt   = (u16*)  (ws + (24u << 20));
    u16*   mid  = (u16*)  (ws + (12u << 20));
    float* hf   = (float*)(ws + (12u << 20));
    u16*   wbuf = (u16*)  (ws + (28u << 20));
    float* bbuf = (float*)(ws + (36u << 20));

    embed_k<<<NROWS, 256, 0, stream>>>(tokens, tok_emb, pos_emb, x);

    for (int l = 0; l < 4; ++l) {
        const size_t wo = (size_t)l * CDIM * CDIM;
        convT_k<<<dim3(16, 16), 256, 0, stream>>>(Wq + wo, wbuf + 0u * CDIM * CDIM, CDIM, CDIM);
        convT_k<<<dim3(16, 16), 256, 0, stream>>>(Wk + wo, wbuf + 1u * CDIM * CDIM, CDIM, CDIM);
        convT_k<<<dim3(16, 16), 256, 0, stream>>>(Wv + wo, wbuf + 2u * CDIM * CDIM, CDIM, CDIM);
        hipMemcpyAsync(bbuf,        bq + l * CDIM, CDIM * 4, hipMemcpyDeviceToDevice, stream);
        hipMemcpyAsync(bbuf + 1024, bk + l * CDIM, CDIM * 4, hipMemcpyDeviceToDevice, stream);
        hipMemcpyAsync(bbuf + 2048, bv + l * CDIM, CDIM * 4, hipMemcpyDeviceToDevice, stream);

        ln_k<true><<<NROWS, 256, 0, stream>>>(x, ln1w + l * CDIM, ln1b + l * CDIM, hbuf);
        gemm_bt<0><<<dim3(24, 32, 1), 256, 0, stream>>>(hbuf, wbuf, bbuf, qkv, nullptr, vt, 3072, CDIM, CDIM);
        attn_k<<<dim3(16, HEADS, 2), 256, 0, stream>>>(qkv, vt, yb);

        convT_k<<<dim3(16, 16), 256, 0, stream>>>(Wp + wo, wbuf, CDIM, CDIM);
        gemm_bt<2><<<dim3(8, 32, 4), 256, 0, stream>>>(yb, wbuf, bp + l * CDIM, nullptr, x, nullptr, CDIM, CDIM, 256);

        ln_k<true><<<NROWS, 256, 0, stream>>>(x, ln2w + l * CDIM, ln2b + l * CDIM, hbuf);
        convT_k<<<dim3(64, 16), 256, 0, stream>>>(W1 + (size_t)l * CDIM * F4, wbuf, CDIM, F4);
        gemm_bt<1><<<dim3(32, 32, 1), 256, 0, stream>>>(hbuf, wbuf, b1 + l * F4, mid, nullptr, nullptr, F4, CDIM, CDIM);
        convT_k<<<dim3(16, 64), 256, 0, stream>>>(W2 + (size_t)l * F4 * CDIM, wbuf, F4, CDIM);
        gemm_bt<2><<<dim3(8, 32, 4), 256, 0, stream>>>(mid, wbuf, b2 + l * CDIM, nullptr, x, nullptr, CDIM, F4, CDIM);
    }

    ln_k<false><<<NROWS, 256, 0, stream>>>(x, lnfw, lnfb, hf);
    head_k<<<NROWS, 256, 0, stream>>>(hf, head_w, out);
}

// Round 5
// 1179.561 us; speedup vs baseline: 1.0482x; 1.0482x over previous
//
#include <hip/hip_runtime.h>
#include <hip/hip_bf16.h>
#include <math.h>

// ---------- common types ----------
typedef unsigned short u16;
typedef __attribute__((ext_vector_type(8))) short short8;  // 8 bf16 = 4 VGPRs (MFMA A/B frag)
typedef __attribute__((ext_vector_type(4))) float f32x4;   // MFMA C/D frag

#define CDIM 1024
#define TDIM 1024
#define NROWS 2048   // B*T
#define HEADS 16
#define HD 64
#define F4 4096

// round-to-nearest-even fp32 -> bf16 bits
__device__ __forceinline__ u16 f2bf(float f) {
    union { float f; unsigned u; } v; v.f = f;
    unsigned r = v.u + 0x7fffu + ((v.u >> 16) & 1u);
    return (u16)(r >> 16);
}

// async global->LDS, 16 bytes per lane; lds base must be wave-uniform
__device__ __forceinline__ void gload_lds16(const void* g, void* lds) {
    __builtin_amdgcn_global_load_lds(
        (const __attribute__((address_space(1))) unsigned int*)g,
        (__attribute__((address_space(3))) unsigned int*)lds,
        16, 0, 0);
}

// ---------- embedding: x = tok_emb[tok] + pos_emb ----------
__global__ __launch_bounds__(256)
void embed_k(const int* __restrict__ tok, const float* __restrict__ te,
             const float* __restrict__ pe, float* __restrict__ X)
{
    const int row = blockIdx.x;          // b*1024 + t
    const int t = row & (TDIM - 1);
    const int tk = tok[row];
    const int c = threadIdx.x * 4;
    float4 a = *reinterpret_cast<const float4*>(te + (size_t)tk * CDIM + c);
    float4 b = *reinterpret_cast<const float4*>(pe + (size_t)t * CDIM + c);
    a.x += b.x; a.y += b.y; a.z += b.z; a.w += b.w;
    *reinterpret_cast<float4*>(X + (size_t)row * CDIM + c) = a;
}

// ---------- layernorm over C=1024, fp32 stats; out bf16 or fp32 ----------
template<bool BF16OUT>
__global__ __launch_bounds__(256)
void ln_k(const float* __restrict__ X, const float* __restrict__ g,
          const float* __restrict__ be, void* __restrict__ outp)
{
    __shared__ float red[4], red2[4];
    const int row = blockIdx.x, tid = threadIdx.x;
    const float* xr = X + (size_t)row * CDIM;
    const int c = tid * 4;
    float4 xv = *reinterpret_cast<const float4*>(xr + c);
    float s  = xv.x + xv.y + xv.z + xv.w;
    float s2 = xv.x*xv.x + xv.y*xv.y + xv.z*xv.z + xv.w*xv.w;
    #pragma unroll
    for (int off = 32; off; off >>= 1) {
        s  += __shfl_xor(s, off);
        s2 += __shfl_xor(s2, off);
    }
    if ((tid & 63) == 0) { red[tid >> 6] = s; red2[tid >> 6] = s2; }
    __syncthreads();
    const float ts  = red[0] + red[1] + red[2] + red[3];
    const float ts2 = red2[0] + red2[1] + red2[2] + red2[3];
    const float mu  = ts * (1.0f / CDIM);
    const float var = ts2 * (1.0f / CDIM) - mu * mu;
    const float rs  = rsqrtf(var + 1e-5f);
    float4 gv = *reinterpret_cast<const float4*>(g + c);
    float4 bv = *reinterpret_cast<const float4*>(be + c);
    float o0 = (xv.x - mu) * rs * gv.x + bv.x;
    float o1 = (xv.y - mu) * rs * gv.y + bv.y;
    float o2 = (xv.z - mu) * rs * gv.z + bv.z;
    float o3 = (xv.w - mu) * rs * gv.w + bv.w;
    if (BF16OUT) {
        u16 tmp[4] = { f2bf(o0), f2bf(o1), f2bf(o2), f2bf(o3) };
        u16* o = (u16*)outp + (size_t)row * CDIM + c;
        *reinterpret_cast<uint2*>(o) = *reinterpret_cast<const uint2*>(tmp);
    } else {
        float4 ov = { o0, o1, o2, o3 };
        *reinterpret_cast<float4*>((float*)outp + (size_t)row * CDIM + c) = ov;
    }
}

// ---------- weight convert+transpose: W[K][N] fp32 -> Wt[N][K] bf16 ----------
__global__ __launch_bounds__(256)
void convT_k(const float* __restrict__ W, u16* __restrict__ Wt,
             const int K, const int N)
{
    __shared__ u16 s[64][72];
    const int k0 = blockIdx.y * 64, n0 = blockIdx.x * 64;
    const int tr = threadIdx.x >> 4, tc = (threadIdx.x & 15) * 4;
    #pragma unroll
    for (int i = 0; i < 4; ++i) {
        int r = tr + i * 16;
        float4 w = *reinterpret_cast<const float4*>(W + (size_t)(k0 + r) * N + n0 + tc);
        s[r][tc + 0] = f2bf(w.x); s[r][tc + 1] = f2bf(w.y);
        s[r][tc + 2] = f2bf(w.z); s[r][tc + 3] = f2bf(w.w);
    }
    __syncthreads();
    #pragma unroll
    for (int i = 0; i < 4; ++i) {
        int n = tr + i * 16;
        u16 tmp[4];
        #pragma unroll
        for (int e = 0; e < 4; ++e) tmp[e] = s[tc + e][n];
        *reinterpret_cast<uint2*>(Wt + (size_t)(n0 + n) * K + k0 + tc) =
            *reinterpret_cast<const uint2*>(tmp);
    }
}

// ---------- GEMM: C[M][N] = A_bf16[M][K] @ Bt_bf16[N][K]^T ----------
// 128x128 tile, 4 waves (2x2), each 64x64 via 4x4 16x16x32 frags.
// Double-buffered LDS, ONE barrier per K-step; grid.z = split-K chunks.
// EPI 0: out bf16 (+V-transpose region if vtout)  EPI 1: gelu->bf16  EPI 2: atomicAdd fp32
template<int EPI>
__global__ __launch_bounds__(256)
void gemm_bt(const u16* __restrict__ A, const u16* __restrict__ Bt,
             const float* __restrict__ bias, u16* __restrict__ outb,
             float* __restrict__ resid, u16* __restrict__ vtout,
             const int N, const int K, const int KCH)
{
    __shared__ __align__(16) u16 sA[2][128 * 32];   // [row][k], 64B/row, NO pad (gload_lds)
    __shared__ __align__(16) u16 sB[2][128 * 32];   // [n][k]
    const int tid = threadIdx.x;
    const int lane = tid & 63, wv = tid >> 6;
    const int m0 = blockIdx.y * 128, n0 = blockIdx.x * 128;
    const int kbeg = blockIdx.z * KCH, kend = kbeg + KCH;
    const int fr = lane & 15, fq = lane >> 4;
    const int wm = wv & 1, wn = wv >> 1;
    const int srow = lane >> 2, schunk = (lane & 3) * 8;  // staging: 4 lanes/row
    f32x4 acc[4][4] = {};

    auto stage = [&](int k0, int buf) {
        #pragma unroll
        for (int i = 0; i < 2; ++i) {
            const int reg = i * 4 + wv;                 // 16-row region
            gload_lds16(A  + (size_t)(m0 + reg * 16 + srow) * K + k0 + schunk,
                        &sA[buf][reg * 512]);
            gload_lds16(Bt + (size_t)(n0 + reg * 16 + srow) * K + k0 + schunk,
                        &sB[buf][reg * 512]);
        }
    };

    stage(kbeg, 0);
    int cur = 0;
    for (int k0 = kbeg; k0 < kend; k0 += 32) {
        __syncthreads();                    // buf[cur] staged (drains vmcnt)
        if (k0 + 32 < kend) stage(k0 + 32, cur ^ 1);   // prefetch next, hidden by compute
        short8 af[4], bf[4];
        #pragma unroll
        for (int mi = 0; mi < 4; ++mi)
            af[mi] = *reinterpret_cast<const short8*>(&sA[cur][(wm * 64 + mi * 16 + fr) * 32 + fq * 8]);
        #pragma unroll
        for (int nj = 0; nj < 4; ++nj)
            bf[nj] = *reinterpret_cast<const short8*>(&sB[cur][(wn * 64 + nj * 16 + fr) * 32 + fq * 8]);
        #pragma unroll
        for (int mi = 0; mi < 4; ++mi)
            #pragma unroll
            for (int nj = 0; nj < 4; ++nj)
                acc[mi][nj] = __builtin_amdgcn_mfma_f32_16x16x32_bf16(af[mi], bf[nj], acc[mi][nj], 0, 0, 0);
        cur ^= 1;
    }

    #pragma unroll
    for (int nj = 0; nj < 4; ++nj) {
        const int col = n0 + wn * 64 + nj * 16 + fr;
        const float bias_v = (EPI == 2 && blockIdx.z != 0) ? 0.0f : bias[col];
        #pragma unroll
        for (int mi = 0; mi < 4; ++mi) {
            const int rowb = m0 + wm * 64 + mi * 16 + fq * 4;
            if (EPI == 0 && vtout != nullptr && col >= 2048) {
                // V part of qkv -> transposed [b*16+h][d][t] bf16, packed 4 t's
                const int bidx = rowb >> 10, t = rowb & 1023, hd = col - 2048;
                u16 t4[4];
                #pragma unroll
                for (int r = 0; r < 4; ++r) t4[r] = f2bf(acc[mi][nj][r] + bias_v);
                *reinterpret_cast<uint2*>(
                    vtout + ((size_t)(bidx * 16 + (hd >> 6)) * 64 + (hd & 63)) * 1024 + t) =
                    *reinterpret_cast<const uint2*>(t4);
            } else {
                #pragma unroll
                for (int r = 0; r < 4; ++r) {
                    const int row = rowb + r;
                    float cv = acc[mi][nj][r] + bias_v;
                    if (EPI == 0) {
                        outb[(size_t)row * N + col] = f2bf(cv);
                    } else if (EPI == 1) {
                        float gl = 0.5f * cv * (1.0f + erff(cv * 0.70710678118654752f));
                        outb[(size_t)row * N + col] = f2bf(gl);
                    } else {
                        atomicAdd(&resid[(size_t)row * N + col], cv);
                    }
                }
            }
        }
    }
}

// ---------- flash attention, shuffle-free softmax ----------
// No running max (scores are O(1); masked -> exp(-1e30)=0; shift cancels in P/l).
// Row-sum l computed by MFMA against an all-ones B fragment. 1 barrier per s-tile.
__global__ __launch_bounds__(256)
void attn_k(const u16* __restrict__ QKV, const u16* __restrict__ VT,
            u16* __restrict__ Y)
{
    __shared__ __align__(16) u16 sQ[64][72];
    __shared__ __align__(16) u16 sK[2][64][72];
    __shared__ __align__(16) u16 sV[2][64][72];   // [d][s]
    __shared__ __align__(16) u16 sP[64][72];
    const int tid = threadIdx.x, lane = tid & 63, wv = tid >> 6;
    const int fr = lane & 15, fq = lane >> 4;
    const int qt = gridDim.x - 1 - blockIdx.x;    // long blocks first
    const int h = blockIdx.y, b = blockIdx.z, q0 = qt * 64;
    const u16* Qb = QKV + (size_t)b * TDIM * 3072 + h * HD;
    const u16* Vb = VT + ((size_t)(b * HEADS + h) * HD) * TDIM;
    const int r0 = tid >> 3, c0 = (tid & 7) * 8;   // staging: 8 chunks/row

    #pragma unroll
    for (int i = 0; i < 2; ++i) {
        const int r = r0 + i * 32;
        *reinterpret_cast<uint4*>(&sQ[r][c0]) =
            *reinterpret_cast<const uint4*>(Qb + (size_t)(q0 + r) * 3072 + c0);
        *reinterpret_cast<uint4*>(&sK[0][r][c0]) =
            *reinterpret_cast<const uint4*>(Qb + 1024 + (size_t)r * 3072 + c0);
        *reinterpret_cast<uint4*>(&sV[0][r][c0]) =
            *reinterpret_cast<const uint4*>(Vb + (size_t)r * TDIM + c0);
    }
    __syncthreads();

    short8 ones;
    #pragma unroll
    for (int e = 0; e < 8; ++e) ones[e] = (short)0x3F80;   // bf16 1.0

    short8 aQ0 = *reinterpret_cast<const short8*>(&sQ[wv * 16 + fr][fq * 8]);
    short8 aQ1 = *reinterpret_cast<const short8*>(&sQ[wv * 16 + fr][32 + fq * 8]);
    f32x4 o[4] = {};
    f32x4 osum = {};

    for (int st = 0; st <= qt; ++st) {
        const int cur = st & 1, s0 = st * 64;
        const bool pf = st < qt;
        uint4 pk[2], pv[2];
        if (pf) {
            #pragma unroll
            for (int i = 0; i < 2; ++i) {
                const int r = r0 + i * 32;
                pk[i] = *reinterpret_cast<const uint4*>(Qb + 1024 + (size_t)(s0 + 64 + r) * 3072 + c0);
                pv[i] = *reinterpret_cast<const uint4*>(Vb + (size_t)r * TDIM + s0 + 64 + c0);
            }
        }
        // S = Q K^T (fp32)
        f32x4 sacc[4] = {};
        #pragma unroll
        for (int j = 0; j < 4; ++j) {
            short8 b0 = *reinterpret_cast<const short8*>(&sK[cur][j * 16 + fr][fq * 8]);
            sacc[j] = __builtin_amdgcn_mfma_f32_16x16x32_bf16(aQ0, b0, sacc[j], 0, 0, 0);
            short8 b1 = *reinterpret_cast<const short8*>(&sK[cur][j * 16 + fr][32 + fq * 8]);
            sacc[j] = __builtin_amdgcn_mfma_f32_16x16x32_bf16(aQ1, b1, sacc[j], 0, 0, 0);
        }
        // mask + scale + exp -> wave-private P rows in LDS (no reductions)
        #pragma unroll
        for (int j = 0; j < 4; ++j)
            #pragma unroll
            for (int r = 0; r < 4; ++r) {
                const int qrow = q0 + wv * 16 + fq * 4 + r;
                const int scol = s0 + j * 16 + fr;
                const bool keep = (scol <= qrow) && ((scol & 15) != 15);
                const float p = keep ? __expf(sacc[j][r] * 0.125f) : 0.0f;
                sP[wv * 16 + fq * 4 + r][j * 16 + fr] = f2bf(p);
            }
        short8 aP0 = *reinterpret_cast<const short8*>(&sP[wv * 16 + fr][fq * 8]);
        short8 aP1 = *reinterpret_cast<const short8*>(&sP[wv * 16 + fr][32 + fq * 8]);
        #pragma unroll
        for (int j = 0; j < 4; ++j) {
            short8 b0 = *reinterpret_cast<const short8*>(&sV[cur][j * 16 + fr][fq * 8]);
            o[j] = __builtin_amdgcn_mfma_f32_16x16x32_bf16(aP0, b0, o[j], 0, 0, 0);
            short8 b1 = *reinterpret_cast<const short8*>(&sV[cur][j * 16 + fr][32 + fq * 8]);
            o[j] = __builtin_amdgcn_mfma_f32_16x16x32_bf16(aP1, b1, o[j], 0, 0, 0);
        }
        osum = __builtin_amdgcn_mfma_f32_16x16x32_bf16(aP0, ones, osum, 0, 0, 0);
        osum = __builtin_amdgcn_mfma_f32_16x16x32_bf16(aP1, ones, osum, 0, 0, 0);
        if (pf) {
            #pragma unroll
            for (int i = 0; i < 2; ++i) {
                const int r = r0 + i * 32;
                *reinterpret_cast<uint4*>(&sK[cur ^ 1][r][c0]) = pk[i];
                *reinterpret_cast<uint4*>(&sV[cur ^ 1][r][c0]) = pv[i];
            }
        }
        __syncthreads();
    }

    float rcp[4];
    #pragma unroll
    for (int r = 0; r < 4; ++r) rcp[r] = 1.0f / osum[r];
    const size_t ybase = ((size_t)b * TDIM + q0) * CDIM + h * HD;
    #pragma unroll
    for (int j = 0; j < 4; ++j)
        #pragma unroll
        for (int r = 0; r < 4; ++r) {
            const int row = wv * 16 + fq * 4 + r, col = j * 16 + fr;
            Y[ybase + (size_t)row * CDIM + col] = f2bf(o[j][r] * rcp[r]);
        }
}

// ---------- head: logits[b,p,o] = sum_i head_w[p%16, o, i] * x[b,p,i] (fp32) ----------
__global__ __launch_bounds__(256)
void head_k(const float* __restrict__ Xf, const float* __restrict__ HW,
            float* __restrict__ out)
{
    const int row = blockIdx.x;               // b*1024 + p
    const int e = row & 15;                   // 1024 % 16 == 0 so row%16 == p%16
    const float* xr = Xf + (size_t)row * CDIM;
    const float* wbase = HW + (size_t)e * 101 * CDIM;
    const int lane = threadIdx.x & 63, wv = threadIdx.x >> 6;
    for (int o = wv; o < 101; o += 4) {
        const float* wr = wbase + (size_t)o * CDIM;
        float s = 0.0f;
        #pragma unroll
        for (int i = 0; i < CDIM / 64; ++i)
            s += xr[lane + i * 64] * wr[lane + i * 64];
        #pragma unroll
        for (int off = 32; off; off >>= 1) s += __shfl_xor(s, off);
        if (lane == 0) out[(size_t)row * 101 + o] = s;
    }
}

// ---------- launch ----------
extern "C" void kernel_launch(void* const* d_in, const int* in_sizes, int n_in,
                              void* d_out, int out_size, void* d_ws, size_t ws_size,
                              hipStream_t stream)
{
    const int*   tokens = (const int*)  d_in[0];
    const float* tok_emb= (const float*)d_in[1];
    const float* pos_emb= (const float*)d_in[2];
    const float* Wq = (const float*)d_in[3];
    const float* bq = (const float*)d_in[4];
    const float* Wk = (const float*)d_in[5];
    const float* bk = (const float*)d_in[6];
    const float* Wv = (const float*)d_in[7];
    const float* bv = (const float*)d_in[8];
    const float* Wp = (const float*)d_in[9];
    const float* bp = (const float*)d_in[10];
    const float* ln1w = (const float*)d_in[11];
    const float* ln1b = (const float*)d_in[12];
    const float* ln2w = (const float*)d_in[13];
    const float* ln2b = (const float*)d_in[14];
    const float* W1 = (const float*)d_in[15];
    const float* b1 = (const float*)d_in[16];
    const float* W2 = (const float*)d_in[17];
    const float* b2 = (const float*)d_in[18];
    const float* lnfw = (const float*)d_in[19];
    const float* lnfb = (const float*)d_in[20];
    const float* head_w = (const float*)d_in[21];
    float* out = (float*)d_out;

    // workspace (36 MB + 12 KB):
    //  0..8M    x fp32 residual
    //  8..12M   hbuf bf16 (LN out) == yb bf16 (attn out; disjoint in time)
    // 12..24M   qkv bf16 [2048][3072] (q,k used)     } alias: mid bf16 [2048][4096] (12..28M),
    // 24..28M   vT bf16 [b*16+h][64][1024]           }        hf fp32 (12..20M, final)
    // 28..36M   wbuf bf16 (converted weights, max 8MB)
    // 36M..     bbuf fp32 [3072]
    char* ws = (char*)d_ws;
    float* x    = (float*)(ws);
    u16*   hbuf = (u16*)  (ws + (8u  << 20));
    u16*   yb   = (u16*)  (ws + (8u  << 20));
    u16*   qkv  = (u16*)  (ws + (12u << 20));
    u16*   vt   = (u16*)  (ws + (24u << 20));
    u16*   mid  = (u16*)  (ws + (12u << 20));
    float* hf   = (float*)(ws + (12u << 20));
    u16*   wbuf = (u16*)  (ws + (28u << 20));
    float* bbuf = (float*)(ws + (36u << 20));

    embed_k<<<NROWS, 256, 0, stream>>>(tokens, tok_emb, pos_emb, x);

    for (int l = 0; l < 4; ++l) {
        const size_t wo = (size_t)l * CDIM * CDIM;
        convT_k<<<dim3(16, 16), 256, 0, stream>>>(Wq + wo, wbuf + 0u * CDIM * CDIM, CDIM, CDIM);
        convT_k<<<dim3(16, 16), 256, 0, stream>>>(Wk + wo, wbuf + 1u * CDIM * CDIM, CDIM, CDIM);
        convT_k<<<dim3(16, 16), 256, 0, stream>>>(Wv + wo, wbuf + 2u * CDIM * CDIM, CDIM, CDIM);
        hipMemcpyAsync(bbuf,        bq + l * CDIM, CDIM * 4, hipMemcpyDeviceToDevice, stream);
        hipMemcpyAsync(bbuf + 1024, bk + l * CDIM, CDIM * 4, hipMemcpyDeviceToDevice, stream);
        hipMemcpyAsync(bbuf + 2048, bv + l * CDIM, CDIM * 4, hipMemcpyDeviceToDevice, stream);

        ln_k<true><<<NROWS, 256, 0, stream>>>(x, ln1w + l * CDIM, ln1b + l * CDIM, hbuf);
        gemm_bt<0><<<dim3(24, 16, 1), 256, 0, stream>>>(hbuf, wbuf, bbuf, qkv, nullptr, vt, 3072, CDIM, CDIM);
        attn_k<<<dim3(16, HEADS, 2), 256, 0, stream>>>(qkv, vt, yb);

        convT_k<<<dim3(16, 16), 256, 0, stream>>>(Wp + wo, wbuf, CDIM, CDIM);
        gemm_bt<2><<<dim3(8, 16, 2), 256, 0, stream>>>(yb, wbuf, bp + l * CDIM, nullptr, x, nullptr, CDIM, CDIM, 512);

        ln_k<true><<<NROWS, 256, 0, stream>>>(x, ln2w + l * CDIM, ln2b + l * CDIM, hbuf);
        convT_k<<<dim3(64, 16), 256, 0, stream>>>(W1 + (size_t)l * CDIM * F4, wbuf, CDIM, F4);
        gemm_bt<1><<<dim3(32, 16, 1), 256, 0, stream>>>(hbuf, wbuf, b1 + l * F4, mid, nullptr, nullptr, F4, CDIM, CDIM);
        convT_k<<<dim3(16, 64), 256, 0, stream>>>(W2 + (size_t)l * F4 * CDIM, wbuf, F4, CDIM);
        gemm_bt<2><<<dim3(8, 16, 4), 256, 0, stream>>>(mid, wbuf, b2 + l * CDIM, nullptr, x, nullptr, CDIM, F4, CDIM);
    }

    ln_k<false><<<NROWS, 256, 0, stream>>>(x, lnfw, lnfb, hf);
    head_k<<<NROWS, 256, 0, stream>>>(hf, head_w, out);
}

// Round 6
// 1124.408 us; speedup vs baseline: 1.0997x; 1.0491x over previous
//
#include <hip/hip_runtime.h>
#include <hip/hip_bf16.h>
#include <math.h>

// ---------- common types ----------
typedef unsigned short u16;
typedef __attribute__((ext_vector_type(8))) short short8;  // 8 bf16 = 4 VGPRs (MFMA A/B frag)
typedef __attribute__((ext_vector_type(4))) float f32x4;   // MFMA C/D frag

#define CDIM 1024
#define TDIM 1024
#define NROWS 2048   // B*T
#define HEADS 16
#define HD 64
#define F4 4096

// round-to-nearest-even fp32 -> bf16 bits
__device__ __forceinline__ u16 f2bf(float f) {
    union { float f; unsigned u; } v; v.f = f;
    unsigned r = v.u + 0x7fffu + ((v.u >> 16) & 1u);
    return (u16)(r >> 16);
}

// async global->LDS, 16 bytes per lane; lds base must be wave-uniform
__device__ __forceinline__ void gload_lds16(const void* g, void* lds) {
    __builtin_amdgcn_global_load_lds(
        (const __attribute__((address_space(1))) unsigned int*)g,
        (__attribute__((address_space(3))) unsigned int*)lds,
        16, 0, 0);
}

// ---------- embedding: x = tok_emb[tok] + pos_emb ----------
__global__ __launch_bounds__(256)
void embed_k(const int* __restrict__ tok, const float* __restrict__ te,
             const float* __restrict__ pe, float* __restrict__ X)
{
    const int row = blockIdx.x;          // b*1024 + t
    const int t = row & (TDIM - 1);
    const int tk = tok[row];
    const int c = threadIdx.x * 4;
    float4 a = *reinterpret_cast<const float4*>(te + (size_t)tk * CDIM + c);
    float4 b = *reinterpret_cast<const float4*>(pe + (size_t)t * CDIM + c);
    a.x += b.x; a.y += b.y; a.z += b.z; a.w += b.w;
    *reinterpret_cast<float4*>(X + (size_t)row * CDIM + c) = a;
}

// ---------- layernorm over C=1024, fp32 stats; out bf16 or fp32 ----------
template<bool BF16OUT>
__global__ __launch_bounds__(256)
void ln_k(const float* __restrict__ X, const float* __restrict__ g,
          const float* __restrict__ be, void* __restrict__ outp)
{
    __shared__ float red[4], red2[4];
    const int row = blockIdx.x, tid = threadIdx.x;
    const float* xr = X + (size_t)row * CDIM;
    const int c = tid * 4;
    float4 xv = *reinterpret_cast<const float4*>(xr + c);
    float s  = xv.x + xv.y + xv.z + xv.w;
    float s2 = xv.x*xv.x + xv.y*xv.y + xv.z*xv.z + xv.w*xv.w;
    #pragma unroll
    for (int off = 32; off; off >>= 1) {
        s  += __shfl_xor(s, off);
        s2 += __shfl_xor(s2, off);
    }
    if ((tid & 63) == 0) { red[tid >> 6] = s; red2[tid >> 6] = s2; }
    __syncthreads();
    const float ts  = red[0] + red[1] + red[2] + red[3];
    const float ts2 = red2[0] + red2[1] + red2[2] + red2[3];
    const float mu  = ts * (1.0f / CDIM);
    const float var = ts2 * (1.0f / CDIM) - mu * mu;
    const float rs  = rsqrtf(var + 1e-5f);
    float4 gv = *reinterpret_cast<const float4*>(g + c);
    float4 bv = *reinterpret_cast<const float4*>(be + c);
    float o0 = (xv.x - mu) * rs * gv.x + bv.x;
    float o1 = (xv.y - mu) * rs * gv.y + bv.y;
    float o2 = (xv.z - mu) * rs * gv.z + bv.z;
    float o3 = (xv.w - mu) * rs * gv.w + bv.w;
    if (BF16OUT) {
        u16 tmp[4] = { f2bf(o0), f2bf(o1), f2bf(o2), f2bf(o3) };
        u16* o = (u16*)outp + (size_t)row * CDIM + c;
        *reinterpret_cast<uint2*>(o) = *reinterpret_cast<const uint2*>(tmp);
    } else {
        float4 ov = { o0, o1, o2, o3 };
        *reinterpret_cast<float4*>((float*)outp + (size_t)row * CDIM + c) = ov;
    }
}

// ---------- weight convert+transpose: W[K][N] fp32 -> Wt[N][K] bf16 ----------
__global__ __launch_bounds__(256)
void convT_k(const float* __restrict__ W, u16* __restrict__ Wt,
             const int K, const int N)
{
    __shared__ u16 s[64][72];
    const int k0 = blockIdx.y * 64, n0 = blockIdx.x * 64;
    const int tr = threadIdx.x >> 4, tc = (threadIdx.x & 15) * 4;
    #pragma unroll
    for (int i = 0; i < 4; ++i) {
        int r = tr + i * 16;
        float4 w = *reinterpret_cast<const float4*>(W + (size_t)(k0 + r) * N + n0 + tc);
        s[r][tc + 0] = f2bf(w.x); s[r][tc + 1] = f2bf(w.y);
        s[r][tc + 2] = f2bf(w.z); s[r][tc + 3] = f2bf(w.w);
    }
    __syncthreads();
    #pragma unroll
    for (int i = 0; i < 4; ++i) {
        int n = tr + i * 16;
        u16 tmp[4];
        #pragma unroll
        for (int e = 0; e < 4; ++e) tmp[e] = s[tc + e][n];
        *reinterpret_cast<uint2*>(Wt + (size_t)(n0 + n) * K + k0 + tc) =
            *reinterpret_cast<const uint2*>(tmp);
    }
}

// ---------- GEMM: C[M][N] = A_bf16[M][K] @ Bt_bf16[N][K]^T ----------
// 128x128 tile, 4 waves (2x2), each 64x64 via 4x4 16x16x32 frags.
// BK=64 per barrier, stored as TWO k-half planes [128][32] to keep m97 banking.
// Double-buffered LDS, ONE barrier per K-step; grid.z = split-K chunks.
// EPI 0: out bf16 (+V-transpose region if vtout)  EPI 1: gelu->bf16  EPI 2: atomicAdd fp32
template<int EPI>
__global__ __launch_bounds__(256, 2)
void gemm_bt(const u16* __restrict__ A, const u16* __restrict__ Bt,
             const float* __restrict__ bias, u16* __restrict__ outb,
             float* __restrict__ resid, u16* __restrict__ vtout,
             const int N, const int K, const int KCH)
{
    __shared__ __align__(16) u16 sA[2][2][128 * 32];   // [buf][khalf][row*32+k]
    __shared__ __align__(16) u16 sB[2][2][128 * 32];
    const int tid = threadIdx.x;
    const int lane = tid & 63, wv = tid >> 6;
    const int m0 = blockIdx.y * 128, n0 = blockIdx.x * 128;
    const int kbeg = blockIdx.z * KCH, kend = kbeg + KCH;
    const int fr = lane & 15, fq = lane >> 4;
    const int wm = wv & 1, wn = wv >> 1;
    const int srow = lane >> 2, schunk = (lane & 3) * 8;  // staging: 4 lanes/row
    f32x4 acc[4][4] = {};

    auto stage = [&](int k0, int buf) {
        #pragma unroll
        for (int kk = 0; kk < 2; ++kk)
            #pragma unroll
            for (int i = 0; i < 2; ++i) {
                const int reg = i * 4 + wv;             // 16-row region, 8 regions
                gload_lds16(A  + (size_t)(m0 + reg * 16 + srow) * K + k0 + kk * 32 + schunk,
                            &sA[buf][kk][reg * 512]);
                gload_lds16(Bt + (size_t)(n0 + reg * 16 + srow) * K + k0 + kk * 32 + schunk,
                            &sB[buf][kk][reg * 512]);
            }
    };

    stage(kbeg, 0);
    int cur = 0;
    for (int k0 = kbeg; k0 < kend; k0 += 64) {
        __syncthreads();                    // buf[cur] staged (drains vmcnt)
        if (k0 + 64 < kend) stage(k0 + 64, cur ^ 1);   // prefetch next, hidden by compute
        #pragma unroll
        for (int kk = 0; kk < 2; ++kk) {
            short8 af[4], bf[4];
            #pragma unroll
            for (int mi = 0; mi < 4; ++mi)
                af[mi] = *reinterpret_cast<const short8*>(
                    &sA[cur][kk][(wm * 64 + mi * 16 + fr) * 32 + fq * 8]);
            #pragma unroll
            for (int nj = 0; nj < 4; ++nj)
                bf[nj] = *reinterpret_cast<const short8*>(
                    &sB[cur][kk][(wn * 64 + nj * 16 + fr) * 32 + fq * 8]);
            #pragma unroll
            for (int mi = 0; mi < 4; ++mi)
                #pragma unroll
                for (int nj = 0; nj < 4; ++nj)
                    acc[mi][nj] = __builtin_amdgcn_mfma_f32_16x16x32_bf16(af[mi], bf[nj], acc[mi][nj], 0, 0, 0);
        }
        cur ^= 1;
    }

    #pragma unroll
    for (int nj = 0; nj < 4; ++nj) {
        const int col = n0 + wn * 64 + nj * 16 + fr;
        const float bias_v = (EPI == 2 && blockIdx.z != 0) ? 0.0f : bias[col];
        #pragma unroll
        for (int mi = 0; mi < 4; ++mi) {
            const int rowb = m0 + wm * 64 + mi * 16 + fq * 4;
            if (EPI == 0 && vtout != nullptr && col >= 2048) {
                // V part of qkv -> transposed [b*16+h][d][t] bf16, packed 4 t's
                const int bidx = rowb >> 10, t = rowb & 1023, hd = col - 2048;
                u16 t4[4];
                #pragma unroll
                for (int r = 0; r < 4; ++r) t4[r] = f2bf(acc[mi][nj][r] + bias_v);
                *reinterpret_cast<uint2*>(
                    vtout + ((size_t)(bidx * 16 + (hd >> 6)) * 64 + (hd & 63)) * 1024 + t) =
                    *reinterpret_cast<const uint2*>(t4);
            } else {
                #pragma unroll
                for (int r = 0; r < 4; ++r) {
                    const int row = rowb + r;
                    float cv = acc[mi][nj][r] + bias_v;
                    if (EPI == 0) {
                        outb[(size_t)row * N + col] = f2bf(cv);
                    } else if (EPI == 1) {
                        float gl = 0.5f * cv * (1.0f + erff(cv * 0.70710678118654752f));
                        outb[(size_t)row * N + col] = f2bf(gl);
                    } else {
                        atomicAdd(&resid[(size_t)row * N + col], cv);
                    }
                }
            }
        }
    }
}

// ---------- flash attention, shuffle-free softmax ----------
// No running max (scores are O(1); masked -> exp(-1e30)=0; shift cancels in P/l).
// Row-sum l computed by MFMA against an all-ones B fragment. 1 barrier per s-tile.
__global__ __launch_bounds__(256)
void attn_k(const u16* __restrict__ QKV, const u16* __restrict__ VT,
            u16* __restrict__ Y)
{
    __shared__ __align__(16) u16 sQ[64][72];
    __shared__ __align__(16) u16 sK[2][64][72];
    __shared__ __align__(16) u16 sV[2][64][72];   // [d][s]
    __shared__ __align__(16) u16 sP[64][72];
    const int tid = threadIdx.x, lane = tid & 63, wv = tid >> 6;
    const int fr = lane & 15, fq = lane >> 4;
    const int qt = gridDim.x - 1 - blockIdx.x;    // long blocks first
    const int h = blockIdx.y, b = blockIdx.z, q0 = qt * 64;
    const u16* Qb = QKV + (size_t)b * TDIM * 3072 + h * HD;
    const u16* Vb = VT + ((size_t)(b * HEADS + h) * HD) * TDIM;
    const int r0 = tid >> 3, c0 = (tid & 7) * 8;   // staging: 8 chunks/row

    #pragma unroll
    for (int i = 0; i < 2; ++i) {
        const int r = r0 + i * 32;
        *reinterpret_cast<uint4*>(&sQ[r][c0]) =
            *reinterpret_cast<const uint4*>(Qb + (size_t)(q0 + r) * 3072 + c0);
        *reinterpret_cast<uint4*>(&sK[0][r][c0]) =
            *reinterpret_cast<const uint4*>(Qb + 1024 + (size_t)r * 3072 + c0);
        *reinterpret_cast<uint4*>(&sV[0][r][c0]) =
            *reinterpret_cast<const uint4*>(Vb + (size_t)r * TDIM + c0);
    }
    __syncthreads();

    short8 ones;
    #pragma unroll
    for (int e = 0; e < 8; ++e) ones[e] = (short)0x3F80;   // bf16 1.0

    short8 aQ0 = *reinterpret_cast<const short8*>(&sQ[wv * 16 + fr][fq * 8]);
    short8 aQ1 = *reinterpret_cast<const short8*>(&sQ[wv * 16 + fr][32 + fq * 8]);
    f32x4 o[4] = {};
    f32x4 osum = {};

    for (int st = 0; st <= qt; ++st) {
        const int cur = st & 1, s0 = st * 64;
        const bool pf = st < qt;
        uint4 pk[2], pv[2];
        if (pf) {
            #pragma unroll
            for (int i = 0; i < 2; ++i) {
                const int r = r0 + i * 32;
                pk[i] = *reinterpret_cast<const uint4*>(Qb + 1024 + (size_t)(s0 + 64 + r) * 3072 + c0);
                pv[i] = *reinterpret_cast<const uint4*>(Vb + (size_t)r * TDIM + s0 + 64 + c0);
            }
        }
        // S = Q K^T (fp32)
        f32x4 sacc[4] = {};
        #pragma unroll
        for (int j = 0; j < 4; ++j) {
            short8 b0 = *reinterpret_cast<const short8*>(&sK[cur][j * 16 + fr][fq * 8]);
            sacc[j] = __builtin_amdgcn_mfma_f32_16x16x32_bf16(aQ0, b0, sacc[j], 0, 0, 0);
            short8 b1 = *reinterpret_cast<const short8*>(&sK[cur][j * 16 + fr][32 + fq * 8]);
            sacc[j] = __builtin_amdgcn_mfma_f32_16x16x32_bf16(aQ1, b1, sacc[j], 0, 0, 0);
        }
        // mask + scale + exp -> wave-private P rows in LDS (no reductions)
        #pragma unroll
        for (int j = 0; j < 4; ++j)
            #pragma unroll
            for (int r = 0; r < 4; ++r) {
                const int qrow = q0 + wv * 16 + fq * 4 + r;
                const int scol = s0 + j * 16 + fr;
                const bool keep = (scol <= qrow) && ((scol & 15) != 15);
                const float p = keep ? __expf(sacc[j][r] * 0.125f) : 0.0f;
                sP[wv * 16 + fq * 4 + r][j * 16 + fr] = f2bf(p);
            }
        short8 aP0 = *reinterpret_cast<const short8*>(&sP[wv * 16 + fr][fq * 8]);
        short8 aP1 = *reinterpret_cast<const short8*>(&sP[wv * 16 + fr][32 + fq * 8]);
        #pragma unroll
        for (int j = 0; j < 4; ++j) {
            short8 b0 = *reinterpret_cast<const short8*>(&sV[cur][j * 16 + fr][fq * 8]);
            o[j] = __builtin_amdgcn_mfma_f32_16x16x32_bf16(aP0, b0, o[j], 0, 0, 0);
            short8 b1 = *reinterpret_cast<const short8*>(&sV[cur][j * 16 + fr][32 + fq * 8]);
            o[j] = __builtin_amdgcn_mfma_f32_16x16x32_bf16(aP1, b1, o[j], 0, 0, 0);
        }
        osum = __builtin_amdgcn_mfma_f32_16x16x32_bf16(aP0, ones, osum, 0, 0, 0);
        osum = __builtin_amdgcn_mfma_f32_16x16x32_bf16(aP1, ones, osum, 0, 0, 0);
        if (pf) {
            #pragma unroll
            for (int i = 0; i < 2; ++i) {
                const int r = r0 + i * 32;
                *reinterpret_cast<uint4*>(&sK[cur ^ 1][r][c0]) = pk[i];
                *reinterpret_cast<uint4*>(&sV[cur ^ 1][r][c0]) = pv[i];
            }
        }
        __syncthreads();
    }

    float rcp[4];
    #pragma unroll
    for (int r = 0; r < 4; ++r) rcp[r] = 1.0f / osum[r];
    const size_t ybase = ((size_t)b * TDIM + q0) * CDIM + h * HD;
    #pragma unroll
    for (int j = 0; j < 4; ++j)
        #pragma unroll
        for (int r = 0; r < 4; ++r) {
            const int row = wv * 16 + fq * 4 + r, col = j * 16 + fr;
            Y[ybase + (size_t)row * CDIM + col] = f2bf(o[j][r] * rcp[r]);
        }
}

// ---------- head: logits[b,p,o] = sum_i head_w[p%16, o, i] * x[b,p,i] (fp32) ----------
__global__ __launch_bounds__(256)
void head_k(const float* __restrict__ Xf, const float* __restrict__ HW,
             float* __restrict__ out)
{
    const int row = blockIdx.x;               // b*1024 + p
    const int e = row & 15;                   // 1024 % 16 == 0 so row%16 == p%16
    const float* xr = Xf + (size_t)row * CDIM;
    const float* wbase = HW + (size_t)e * 101 * CDIM;
    const int lane = threadIdx.x & 63, wv = threadIdx.x >> 6;
    for (int o = wv; o < 101; o += 4) {
        const float* wr = wbase + (size_t)o * CDIM;
        float s = 0.0f;
        #pragma unroll
        for (int i = 0; i < CDIM / 64; ++i)
            s += xr[lane + i * 64] * wr[lane + i * 64];
        #pragma unroll
        for (int off = 32; off; off >>= 1) s += __shfl_xor(s, off);
        if (lane == 0) out[(size_t)row * 101 + o] = s;
    }
}

// ---------- launch ----------
extern "C" void kernel_launch(void* const* d_in, const int* in_sizes, int n_in,
                              void* d_out, int out_size, void* d_ws, size_t ws_size,
                              hipStream_t stream)
{
    const int*   tokens = (const int*)  d_in[0];
    const float* tok_emb= (const float*)d_in[1];
    const float* pos_emb= (const float*)d_in[2];
    const float* Wq = (const float*)d_in[3];
    const float* bq = (const float*)d_in[4];
    const float* Wk = (const float*)d_in[5];
    const float* bk = (const float*)d_in[6];
    const float* Wv = (const float*)d_in[7];
    const float* bv = (const float*)d_in[8];
    const float* Wp = (const float*)d_in[9];
    const float* bp = (const float*)d_in[10];
    const float* ln1w = (const float*)d_in[11];
    const float* ln1b = (const float*)d_in[12];
    const float* ln2w = (const float*)d_in[13];
    const float* ln2b = (const float*)d_in[14];
    const float* W1 = (const float*)d_in[15];
    const float* b1 = (const float*)d_in[16];
    const float* W2 = (const float*)d_in[17];
    const float* b2 = (const float*)d_in[18];
    const float* lnfw = (const float*)d_in[19];
    const float* lnfb = (const float*)d_in[20];
    const float* head_w = (const float*)d_in[21];
    float* out = (float*)d_out;

    // workspace (36 MB + 12 KB):
    //  0..8M    x fp32 residual
    //  8..12M   hbuf bf16 (LN out) == yb bf16 (attn out; disjoint in time)
    // 12..24M   qkv bf16 [2048][3072] (q,k used)     } alias: mid bf16 [2048][4096] (12..28M),
    // 24..28M   vT bf16 [b*16+h][64][1024]           }        hf fp32 (12..20M, final)
    // 28..36M   wbuf bf16 (converted weights, max 8MB)
    // 36M..     bbuf fp32 [3072]
    char* ws = (char*)d_ws;
    float* x    = (float*)(ws);
    u16*   hbuf = (u16*)  (ws + (8u  << 20));
    u16*   yb   = (u16*)  (ws + (8u  << 20));
    u16*   qkv  = (u16*)  (ws + (12u << 20));
    u16*   vt   = (u16*)  (ws + (24u << 20));
    u16*   mid  = (u16*)  (ws + (12u << 20));
    float* hf   = (float*)(ws + (12u << 20));
    u16*   wbuf = (u16*)  (ws + (28u << 20));
    float* bbuf = (float*)(ws + (36u << 20));

    embed_k<<<NROWS, 256, 0, stream>>>(tokens, tok_emb, pos_emb, x);

    for (int l = 0; l < 4; ++l) {
        const size_t wo = (size_t)l * CDIM * CDIM;
        convT_k<<<dim3(16, 16), 256, 0, stream>>>(Wq + wo, wbuf + 0u * CDIM * CDIM, CDIM, CDIM);
        convT_k<<<dim3(16, 16), 256, 0, stream>>>(Wk + wo, wbuf + 1u * CDIM * CDIM, CDIM, CDIM);
        convT_k<<<dim3(16, 16), 256, 0, stream>>>(Wv + wo, wbuf + 2u * CDIM * CDIM, CDIM, CDIM);
        hipMemcpyAsync(bbuf,        bq + l * CDIM, CDIM * 4, hipMemcpyDeviceToDevice, stream);
        hipMemcpyAsync(bbuf + 1024, bk + l * CDIM, CDIM * 4, hipMemcpyDeviceToDevice, stream);
        hipMemcpyAsync(bbuf + 2048, bv + l * CDIM, CDIM * 4, hipMemcpyDeviceToDevice, stream);

        ln_k<true><<<NROWS, 256, 0, stream>>>(x, ln1w + l * CDIM, ln1b + l * CDIM, hbuf);
        gemm_bt<0><<<dim3(24, 16, 1), 256, 0, stream>>>(hbuf, wbuf, bbuf, qkv, nullptr, vt, 3072, CDIM, CDIM);
        attn_k<<<dim3(16, HEADS, 2), 256, 0, stream>>>(qkv, vt, yb);

        convT_k<<<dim3(16, 16), 256, 0, stream>>>(Wp + wo, wbuf, CDIM, CDIM);
        gemm_bt<2><<<dim3(8, 16, 2), 256, 0, stream>>>(yb, wbuf, bp + l * CDIM, nullptr, x, nullptr, CDIM, CDIM, 512);

        ln_k<true><<<NROWS, 256, 0, stream>>>(x, ln2w + l * CDIM, ln2b + l * CDIM, hbuf);
        convT_k<<<dim3(64, 16), 256, 0, stream>>>(W1 + (size_t)l * CDIM * F4, wbuf, CDIM, F4);
        gemm_bt<1><<<dim3(32, 16, 1), 256, 0, stream>>>(hbuf, wbuf, b1 + l * F4, mid, nullptr, nullptr, F4, CDIM, CDIM);
        convT_k<<<dim3(16, 64), 256, 0, stream>>>(W2 + (size_t)l * F4 * CDIM, wbuf, F4, CDIM);
        gemm_bt<2><<<dim3(8, 16, 4), 256, 0, stream>>>(mid, wbuf, b2 + l * CDIM, nullptr, x, nullptr, CDIM, F4, CDIM);
    }

    ln_k<false><<<NROWS, 256, 0, stream>>>(x, lnfw, lnfb, hf);
    head_k<<<NROWS, 256, 0, stream>>>(hf, head_w, out);
}